// Round 1
// baseline (339.958 us; speedup 1.0000x reference)
//
#include <hip/hip_runtime.h>
#include <stdint.h>

// Problem constants (CorrelationModule): x[8,384,48,48], O=512, N=48*48=2304
#define B_    8
#define CIN   384
#define OCH   512
#define NTOK  2304
#define SCALE 0.044194173824159216f  // 1/sqrt(512)

typedef unsigned short u16;
typedef u16   u16x8 __attribute__((ext_vector_type(8)));
typedef short s16x8 __attribute__((ext_vector_type(8)));
typedef float f32x4 __attribute__((ext_vector_type(4)));

// ---------- bf16 helpers (bit-level, RNE) ----------
__device__ __forceinline__ u16 f2bf(float f) {
    union { uint32_t i; float f; } v; v.f = f;
    uint32_t r = v.i + 0x7fffu + ((v.i >> 16) & 1u);
    return (u16)(r >> 16);
}

// ---------- async global->LDS (width 16) ----------
typedef __attribute__((address_space(1))) const uint32_t glb_u32;
typedef __attribute__((address_space(3))) uint32_t lds_u32;

// =====================================================================
// BRICK FORMAT for all bf16 intermediates (see R6/R7 provenance).
// brick (g, c) = rows g*16..+16, cols c*32..+32, 512 u16, chunk l (16 B)
// = (col8 = l>>4, row = l&15).  u16 offset of (row, col) inside brick:
//   ((col>>3)&3)*128 + (row&15)*8 + (col&7)
// =====================================================================
__device__ __forceinline__ size_t baddr(int row, int col, int Kc) {
    return ((size_t)(row >> 4) * (Kc >> 5) + (col >> 5)) * 512
         + (size_t)(((col >> 3) & 3) * 128 + (row & 15) * 8 + (col & 7));
}

// stage a 128x32 brick-format tile (rows row0..+128, cols k0..+32) into LDS
__device__ __forceinline__ void stage_blocked(const u16* __restrict__ base,
                                              int row0, int k0, int Kc,
                                              u16* __restrict__ dst, int t)
{
    const int lane = t & 63;
    const int w = t >> 6;
    const int bpr = Kc >> 5;
#pragma unroll
    for (int it = 0; it < 2; ++it) {
        const int ck = w * 2 + it;               // 0..7 (16-row groups)
        const u16* gp = base + ((size_t)((row0 >> 4) + ck) * bpr + (k0 >> 5)) * 512
                      + (size_t)lane * 8;
        u16* lp = dst + ck * 512;                // wave-uniform base
        __builtin_amdgcn_global_load_lds((glb_u32*)gp, (lds_u32*)lp, 16, 0, 0);
    }
}

// 2x2-wave 128x128 MFMA core (16 MFMA/wave per BK=32 step; proven R6/R7)
__device__ __forceinline__ void mfma_core(const u16* __restrict__ As,
                                          const u16* __restrict__ Bs,
                                          int wm16, int wn16, int lrow, int kq,
                                          f32x4 acc[4][4])
{
    s16x8 a[4], b[4];
#pragma unroll
    for (int i = 0; i < 4; ++i)
        a[i] = *(const s16x8*)(As + (((wm16 + i) * 64) + kq * 16 + lrow) * 8);
#pragma unroll
    for (int j = 0; j < 4; ++j)
        b[j] = *(const s16x8*)(Bs + (((wn16 + j) * 64) + kq * 16 + lrow) * 8);
#pragma unroll
    for (int i = 0; i < 4; ++i)
#pragma unroll
        for (int j = 0; j < 4; ++j)
            acc[i][j] = __builtin_amdgcn_mfma_f32_16x16x32_bf16(a[i], b[j], acc[i][j], 0, 0, 0);
}

// =====================================================================
// R8: LDS-repack epilogue.  The old epilogue did 64 scattered 2-B global
// stores/thread (128 B/instr, 8 segments) + per-element baddr math —
// ~1/3 of each GEMM kernel's time (logits: 588 TF vs ~850 TF K-loop).
// New: after the K-loop As/Bs (16 KB) are dead; reuse as a 128x64
// half-tile (two rounds, j-pair 0/1 then 2/3).  Lanes ds_write_b16 into
// a row-major tile with chunk-XOR swizzle (chunk ^ (row&7)) -> ~2-way
// bank aliasing (free, m136); reader applies the same XOR, reads 16-B
// chunks with ds_read_b128 and writes 4 global dwordx4/thread/round.
// Per wave each store instr covers one full 1-KB brick contiguously.
// MODE: 0 = logits (exp + rowsum), 1 = +bias[col], 2 = +bias[row],
//       3 = *scale[row]
// =====================================================================
template <int MODE>
__device__ __forceinline__ void brick_epilogue(
    u16* Cs, u16* __restrict__ Cg, const f32x4 (&acc)[4][4],
    const float* __restrict__ aux, float* rowsumL,
    int m0, int n0, int N, int t)
{
    const int w = t >> 6, ln = t & 63;
    const int wm16 = (w & 1) * 4;
    const int wh   = (w >> 1);            // col-half of this wave (0/1)
    const int lrow = ln & 15, kq = ln >> 4;
    const int bpr  = N >> 5;
    // reader-side lane constants (wave-uniform where required)
    const int rr  = t & 15;               // row within 16-group
    const int cc2 = (t >> 4) & 3;         // col-chunk within brick
    const int hb  = (t >> 6) & 1;         // which of the 2 col-bricks (wave-uniform)
    const int gw  = t >> 7;               // row-group parity (wave-uniform)

    float bcol[4];
    if (MODE == 1) {
#pragma unroll
        for (int j = 0; j < 4; ++j)
            bcol[j] = aux[n0 + (wh * 4 + j) * 16 + lrow];
    }

#pragma unroll
    for (int h = 0; h < 2; ++h) {
        if (h) __syncthreads();           // round-0 reads done before overwrite
#pragma unroll
        for (int i = 0; i < 4; ++i) {
            const int rl = (wm16 + i) * 16 + kq * 4;
#pragma unroll
            for (int r = 0; r < 4; ++r) {
                const int row = rl + r;   // local row 0..127
                float radd = 0.f, rmul = 1.f, part = 0.f;
                if (MODE == 2) radd = aux[m0 + row];
                if (MODE == 3) rmul = 1.0f / aux[m0 + row];
#pragma unroll
                for (int jj = 0; jj < 2; ++jj) {
                    const int j = h * 2 + jj;
                    float v = acc[i][j][r];
                    if (MODE == 0) { v = __expf(v * SCALE); part += v; }
                    if (MODE == 1) v += bcol[j];
                    if (MODE == 2) v += radd;
                    if (MODE == 3) v *= rmul;
                    const int clh  = wh * 32 + jj * 16 + lrow;          // 0..63
                    const int slot = ((clh >> 3) ^ (row & 7)) & 7;
                    Cs[row * 64 + (slot << 3) + (clh & 7)] = f2bf(v);
                }
                if (MODE == 0) {
                    part += __shfl_xor(part, 1);
                    part += __shfl_xor(part, 2);
                    part += __shfl_xor(part, 4);
                    part += __shfl_xor(part, 8);
                    if (lrow == 0) atomicAdd(&rowsumL[row], part);
                }
            }
        }
        __syncthreads();
        // store half-tile: 1024 chunks, 4/thread; wave covers one brick/iter
#pragma unroll
        for (int kk = 0; kk < 4; ++kk) {
            const int g  = kk * 2 + gw;       // row-group 0..7
            const int R  = g * 16 + rr;       // local row
            const int lc = hb * 4 + cc2;      // half-local chunk 0..7
            const int slot = (lc ^ (R & 7)) & 7;
            u16x8 v = *(const u16x8*)(Cs + R * 64 + (slot << 3));
            size_t go = ((size_t)((m0 + R) >> 4) * bpr + (n0 >> 5) + h + (lc >> 2) * 2) * 512
                      + (size_t)((lc & 3) * 128 + (R & 15) * 8);
            *(u16x8*)(Cg + go) = v;
        }
    }
}

// =====================================================================
// Kernel 0a: weight cast fp32 -> bf16, BRICK output.
// =====================================================================
#define WQKV_SZ (OCH * CIN)
#define WO_SZ   (OCH * OCH)
#define CH_QKV  (WQKV_SZ / 8)
#define CH_WO   (WO_SZ / 8)
#define CH_TOT  (3 * CH_QKV + CH_WO)

__global__ __launch_bounds__(256) void prep_w_kernel(
    const float* __restrict__ Wq, const float* __restrict__ Wk,
    const float* __restrict__ Wv, const float* __restrict__ Wo,
    u16* __restrict__ Wqb, u16* __restrict__ Wkb,
    u16* __restrict__ Wvb, u16* __restrict__ Wob)
{
    int lc = blockIdx.x * 256 + threadIdx.x;
    if (lc >= CH_TOT) return;
    const float* src; u16* dst; int Kc;
    if      (lc < CH_QKV)     { src = Wq; dst = Wqb; Kc = CIN; }
    else if (lc < 2 * CH_QKV) { src = Wk; dst = Wkb; Kc = CIN; lc -= CH_QKV; }
    else if (lc < 3 * CH_QKV) { src = Wv; dst = Wvb; Kc = CIN; lc -= 2 * CH_QKV; }
    else                      { src = Wo; dst = Wob; Kc = OCH; lc -= 3 * CH_QKV; }
    const int brick = lc >> 6, l = lc & 63;
    const int bpr = Kc >> 5;
    const int g = brick / bpr, c = brick % bpr;
    const int row = g * 16 + (l & 15);
    const int col = c * 32 + (l >> 4) * 8;
    const float* s = src + (size_t)row * Kc + col;
    float4 v0 = *(const float4*)s;
    float4 v1 = *(const float4*)(s + 4);
    u16x8 o;
    o[0] = f2bf(v0.x); o[1] = f2bf(v0.y); o[2] = f2bf(v0.z); o[3] = f2bf(v0.w);
    o[4] = f2bf(v1.x); o[5] = f2bf(v1.y); o[6] = f2bf(v1.z); o[7] = f2bf(v1.w);
    *(u16x8*)(dst + (size_t)lc * 8) = o;
}

// =====================================================================
// Kernel 0b: transpose x [B,C,N] fp32 -> xT [B,N,C] bf16 BRICK.
// =====================================================================
__global__ __launch_bounds__(256) void transpose_x_kernel(
    const float* __restrict__ x, u16* __restrict__ xT)
{
    const int n0 = blockIdx.x * 64;
    const int c0 = blockIdx.y * 64;
    const int b  = blockIdx.z;
    const float* X = x + (size_t)b * CIN * NTOK;

    __shared__ float Ts[64][66];

    const int t = threadIdx.x;
#pragma unroll
    for (int rep = 0; rep < 4; ++rep) {
        const int cr = (t >> 4) + rep * 16;
        const int n4 = (t & 15) * 4;
        float4 v = *(const float4*)(X + (size_t)(c0 + cr) * NTOK + n0 + n4);
        *(float2*)&Ts[cr][n4]     = make_float2(v.x, v.y);
        *(float2*)&Ts[cr][n4 + 2] = make_float2(v.z, v.w);
    }
    __syncthreads();

    u16* O = xT + (size_t)b * NTOK * CIN;
#pragma unroll
    for (int rep = 0; rep < 2; ++rep) {
        const int nr = (t >> 3) + rep * 32;
        const int c8 = (t & 7) * 8;
        u16 tmp[8];
#pragma unroll
        for (int j = 0; j < 8; ++j) tmp[j] = f2bf(Ts[c8 + j][nr]);
        *(u16x8*)(O + baddr(n0 + nr, c0 + c8, CIN)) = *(const u16x8*)tmp;
    }
}

// =====================================================================
// Merged Q+K projection (128x128, brick in/out): z = which*8 + batch.
// =====================================================================
__global__ __launch_bounds__(256) void qk_kernel(
    const u16* __restrict__ xT,
    const u16* __restrict__ Wqb, const float* __restrict__ bq,
    const u16* __restrict__ Wkb, const float* __restrict__ bk,
    u16* __restrict__ Qt, u16* __restrict__ Kt)
{
    const int zz  = blockIdx.x % 16;
    const int b   = zz & 7, which = zz >> 3;
    const int rem = blockIdx.x / 16;
    const int n0 = (rem % 4) * 128;
    const int m0 = (rem / 4) * 128;
    const u16* A  = xT + (size_t)b * NTOK * CIN;
    const u16* Bp = which ? Wkb : Wqb;
    const float* bias = which ? bk : bq;
    u16* C = (which ? Kt : Qt) + (size_t)b * NTOK * OCH;

    __shared__ u16 smem[128 * 64];           // As | Bs during K-loop; Cs after
    u16* As = smem;
    u16* Bs = smem + 128 * 32;

    const int t = threadIdx.x;
    const int w = t >> 6, ln = t & 63;
    const int wm16 = (w & 1) * 4, wn16 = (w >> 1) * 4;
    const int lrow = ln & 15, kq = ln >> 4;

    f32x4 acc[4][4] = {};

    for (int k0 = 0; k0 < CIN; k0 += 32) {
        stage_blocked(A, m0, k0, CIN, As, t);
        stage_blocked(Bp, n0, k0, CIN, Bs, t);
        __syncthreads();
        mfma_core(As, Bs, wm16, wn16, lrow, kq, acc);
        __syncthreads();
    }

    brick_epilogue<1>(smem, C, acc, bias, nullptr, m0, n0, OCH, t);
}

// =====================================================================
// Generic MFMA GEMM (128x128, brick A/B): C[m][n] = sum_k A[m][k]*B[n][k]
// BIAS: 1 row bias.  OutT u16 -> brick C (repack epilogue);
// float -> row-major C (direct stores, 64-B segments).
// =====================================================================
template <int BIAS, typename OutT>
__global__ __launch_bounds__(256) void gemm_kernel(
    const u16* __restrict__ Ag, const u16* __restrict__ Bg,
    const float* __restrict__ bias, OutT* __restrict__ Cg,
    int K, int N, long sA, long sB, long sC, int GX, int GZ)
{
    const int z   = blockIdx.x % GZ;
    const int rem = blockIdx.x / GZ;
    const int n0 = (rem % GX) * 128;
    const int m0 = (rem / GX) * 128;
    const u16* A  = Ag + (size_t)z * sA;
    const u16* Bp = Bg + (size_t)z * sB;
    OutT* C = Cg + (size_t)z * sC;

    __shared__ u16 smem[128 * 64];
    u16* As = smem;
    u16* Bs = smem + 128 * 32;

    const int t = threadIdx.x;
    const int w = t >> 6, ln = t & 63;
    const int wm16 = (w & 1) * 4, wn16 = (w >> 1) * 4;
    const int lrow = ln & 15, kq = ln >> 4;

    f32x4 acc[4][4] = {};

    for (int k0 = 0; k0 < K; k0 += 32) {
        stage_blocked(A, m0, k0, K, As, t);
        stage_blocked(Bp, n0, k0, K, Bs, t);
        __syncthreads();
        mfma_core(As, Bs, wm16, wn16, lrow, kq, acc);
        __syncthreads();
    }

    if constexpr (sizeof(OutT) == 2) {
        brick_epilogue<2>(smem, (u16*)C, acc, bias, nullptr, m0, n0, N, t);
    } else {
#pragma unroll
        for (int i = 0; i < 4; ++i) {
            const int row = m0 + (wm16 + i) * 16 + kq * 4;
#pragma unroll
            for (int r = 0; r < 4; ++r) {
                float badd = 0.f;
                if (BIAS == 1) badd = bias[row + r];
#pragma unroll
                for (int j = 0; j < 4; ++j) {
                    const int col = n0 + (wn16 + j) * 16 + lrow;
                    C[(size_t)(row + r) * N + col] = acc[i][j][r] + badd;
                }
            }
        }
    }
}

// =====================================================================
// Logits+exp kernel (128x128, brick): E[n][m] = exp(SCALE * Qt[n].Kt[m]);
// rowsumG[z][n] += partial row sums (fp32 device atomics).
// =====================================================================
__global__ __launch_bounds__(256) void logits_exp_kernel(
    const u16* __restrict__ Qt, const u16* __restrict__ Kt,
    u16* __restrict__ Ew, float* __restrict__ rowsumG)
{
    const int z   = blockIdx.x % B_;
    const int rem = blockIdx.x / B_;
    const int n0 = (rem % (NTOK / 128)) * 128;   // Kt token tiles, fast
    const int m0 = (rem / (NTOK / 128)) * 128;   // Qt token tiles
    const u16* A  = Qt + (size_t)z * NTOK * OCH;
    const u16* Bp = Kt + (size_t)z * NTOK * OCH;

    __shared__ u16 smem[128 * 64];
    __shared__ float rowsumL[128];
    u16* As = smem;
    u16* Bs = smem + 128 * 32;

    const int t = threadIdx.x;
    const int w = t >> 6, ln = t & 63;
    const int wm16 = (w & 1) * 4, wn16 = (w >> 1) * 4;
    const int lrow = ln & 15, kq = ln >> 4;

    if (t < 128) rowsumL[t] = 0.f;

    f32x4 acc[4][4] = {};

    for (int k0 = 0; k0 < OCH; k0 += 32) {
        stage_blocked(A, m0, k0, OCH, As, t);
        stage_blocked(Bp, n0, k0, OCH, Bs, t);
        __syncthreads();
        mfma_core(As, Bs, wm16, wn16, lrow, kq, acc);
        __syncthreads();
    }

    u16* E = Ew + (size_t)z * NTOK * NTOK;
    brick_epilogue<0>(smem, E, acc, nullptr, rowsumL, m0, n0, NTOK, t);

    __syncthreads();
    if (t < 128) atomicAdd(&rowsumG[(size_t)z * NTOK + m0 + t], rowsumL[t]);
}

// =====================================================================
// PV kernel (128x128, brick): AOt[n][o] = (sum_m E[n][m]*V[o][m]) / rowsum
// =====================================================================
__global__ __launch_bounds__(256) void pv_div_kernel(
    const u16* __restrict__ Ew, const u16* __restrict__ Vw,
    const float* __restrict__ rowsumG, u16* __restrict__ AOt)
{
    const int z   = blockIdx.x % B_;
    const int rem = blockIdx.x / B_;
    const int n0 = (rem % 4) * 128;              // o tiles, fast
    const int m0 = (rem / 4) * 128;              // token tiles
    const u16* A  = Ew + (size_t)z * NTOK * NTOK;
    const u16* Bp = Vw + (size_t)z * OCH * NTOK;

    __shared__ u16 smem[128 * 64];
    u16* As = smem;
    u16* Bs = smem + 128 * 32;

    const int t = threadIdx.x;
    const int w = t >> 6, ln = t & 63;
    const int wm16 = (w & 1) * 4, wn16 = (w >> 1) * 4;
    const int lrow = ln & 15, kq = ln >> 4;

    f32x4 acc[4][4] = {};

    for (int k0 = 0; k0 < NTOK; k0 += 32) {
        stage_blocked(A, m0, k0, NTOK, As, t);
        stage_blocked(Bp, n0, k0, NTOK, Bs, t);
        __syncthreads();
        mfma_core(As, Bs, wm16, wn16, lrow, kq, acc);
        __syncthreads();
    }

    u16* AO = AOt + (size_t)z * NTOK * OCH;
    brick_epilogue<3>(smem, AO, acc, rowsumG + (size_t)z * NTOK, nullptr,
                      m0, n0, OCH, t);
}

// =====================================================================
extern "C" void kernel_launch(void* const* d_in, const int* in_sizes, int n_in,
                              void* d_out, int out_size, void* d_ws, size_t ws_size,
                              hipStream_t stream)
{
    const float* x  = (const float*)d_in[0];
    const float* Wq = (const float*)d_in[1];
    const float* bq = (const float*)d_in[2];
    const float* Wk = (const float*)d_in[3];
    const float* bk = (const float*)d_in[4];
    const float* Wv = (const float*)d_in[5];
    const float* bv = (const float*)d_in[6];
    const float* Wo = (const float*)d_in[7];
    const float* bo = (const float*)d_in[8];
    float* out = (float*)d_out;

    u16* ws = (u16*)d_ws;
    u16* Wqb = ws;
    u16* Wkb = Wqb + WQKV_SZ;
    u16* Wvb = Wkb + WQKV_SZ;
    u16* Wob = Wvb + WQKV_SZ;
    u16* xT  = Wob + WO_SZ;
    const size_t xtsz  = (size_t)B_ * NTOK * CIN;
    const size_t qkvsz = (size_t)B_ * NTOK * OCH;
    u16* Qt  = xT + xtsz;
    u16* Kt  = Qt + qkvsz;
    u16* Vw  = Kt + qkvsz;
    u16* Ew  = Vw + qkvsz;                          // B*N*N
    float* rowsumG = (float*)(Ew + (size_t)B_ * NTOK * NTOK);
    u16* AOt = Qt;                                  // alias: Qt dead after logits
    // total approx 157.5 MB

    dim3 blk(256);

    prep_w_kernel<<<dim3((CH_TOT + 255) / 256), blk, 0, stream>>>(
        Wq, Wk, Wv, Wo, Wqb, Wkb, Wvb, Wob);
    transpose_x_kernel<<<dim3(NTOK / 64, CIN / 64, B_), blk, 0, stream>>>(x, xT);
    hipMemsetAsync(rowsumG, 0, (size_t)B_ * NTOK * sizeof(float), stream);

    // Q & K merged: 4 o-tiles x 18 token-tiles x 16 (which*8+batch) = 1152
    qk_kernel<<<dim3(4 * 18 * 16), blk, 0, stream>>>(
        xT, Wqb, bq, Wkb, bk, Qt, Kt);
    // V[o][m] = Wv[o].xT[m] + bv[o]: 18 n-tiles (fast) x 4 m-tiles x 8 = 576
    gemm_kernel<1, u16><<<dim3(18 * 4 * B_), blk, 0, stream>>>(
        Wvb, xT, bv, Vw, CIN, NTOK, 0L, (long)NTOK * CIN, (long)OCH * NTOK, 18, B_);

    // E = exp(scale * Qt.Kt^T), rowsumG += row sums  (18x18x8 = 2592)
    logits_exp_kernel<<<dim3(18 * 18 * B_), blk, 0, stream>>>(Qt, Kt, Ew, rowsumG);

    // AOt = (E.V^T) / rowsum: 4 o-tiles (fast) x 18 token-tiles x 8 = 576
    pv_div_kernel<<<dim3(4 * 18 * B_), blk, 0, stream>>>(Ew, Vw, rowsumG, AOt);

    // out[p][n] = Wo[p].AOt[n] + bo[p]: 18 n-tiles (fast) x 4 p-tiles x 8 = 576
    gemm_kernel<1, float><<<dim3(18 * 4 * B_), blk, 0, stream>>>(
        Wob, AOt, bo, out, OCH, NTOK, 0L, (long)NTOK * OCH, (long)OCH * NTOK, 18, B_);
}